// Round 6
// baseline (236.920 us; speedup 1.0000x reference)
//
#include <hip/hip_runtime.h>

// HexConv2d implicit GEMM, bf16 MFMA 16x16x32.
// v12: 4-wave/SIMD cross-block config. Evidence: v6 (1 w/SIMD) and v11
// (~3 w/SIMD, ragged 768+256 packing) both = 79 us, MfmaUtil 40%. No config
// yet ran >=4 desynced waves/SIMD: v10 was reg-blocked (152 regs -> second
// block never fit), v11 was 148 regs (>128) + ragged rounds.
// v12: och split across blocks. Wave = 32och x 80px -> acc[2][5] = 40 acc,
// arch ~64 -> ~104 <= 128 -> 4 waves/SIMD (launch_bounds(256,4)).
// Single-kc staging (12KB buf, 24KB dbuf) -> 4 blocks/CU = 16 waves/CU, each
// block at a different kc phase (stagger by pt,b,oh) = desynced barriers.
// Grid 32pt x 2oh x 32b = 2048 = EXACTLY 2 rounds of 4/CU (no ragged tail).
// Per-block weight reads halve (459KB); oh pairs dispatched adjacently so the
// second half's xb staging hits L2/L3. xb layout/swizzle/staging/prep all
// byte-identical to v11 (0 bank conflicts, verified).

typedef __attribute__((ext_vector_type(8))) short short8;
typedef __attribute__((ext_vector_type(4))) short short4v;
typedef __attribute__((ext_vector_type(4))) float floatx4;

#define NPIX   2401
#define W50    50
#define PREAL  2450      // 49 rows * 50
#define XBLEAD 56
#define XBROWS 2672      // padded rows per batch: [-56, 2616)
#define PT12   80        // pixels per block
#define NT12   32        // 32*80 = 2560 >= 2450
#define NSEG12 12        // 192 window rows: [P0-56, P0+136)
#define BUF12  (NSEG12*1024)      // 12288 B per buffer (1 kc)
#define XB3_BYTES ((size_t)32*XBROWS*256*2)   // 43,778,048
#define WP_BYTES  917504ULL
#define WS_NEED3  (XB3_BYTES + WP_BYTES)
#define NPADROW 271      // 56 apron + 49 col-49 + 166 tail rows per batch

// merged-prep block ranges
#define X4_BLKS 4864     // 38*4*32
#define Z_BLKS  1084     // 32*271*32 / 256 = 1084 exactly
#define W_BLKS  224
#define PREP_BLKS (X4_BLKS + Z_BLKS + W_BLKS)   // 6172

__device__ __forceinline__ unsigned short f2bf(float f) {
  unsigned u = __builtin_bit_cast(unsigned, f);
  u += 0x7fffu + ((u >> 16) & 1u);          // RNE
  return (unsigned short)(u >> 16);
}

__device__ __forceinline__ void prep_w_body(const float* __restrict__ w,
                                            unsigned short* __restrict__ wp, int tt) {
  int l  = tt & 63;
  int ot = (tt >> 6) & 15;
  int kc = (tt >> 10) & 7;
  int n  = tt >> 13;
  int o  = ot * 16 + (l & 15);
  int cb = kc * 32 + ((l >> 4) * 8);
  const float* src = w + (size_t)(o * 256 + cb) * 7 + n;
  short8 pk;
#pragma unroll
  for (int j = 0; j < 8; ++j) pk[j] = (short)f2bf(src[j * 7]);
  ((short8*)wp)[tt] = pk;
}

// ---------------- merged prep: x-transpose | pad-zero | w-pack ----------------
__global__ __launch_bounds__(256)
void prep_all(const float* __restrict__ x, const float* __restrict__ w,
              unsigned short* __restrict__ xb, unsigned short* __restrict__ wp) {
  __shared__ unsigned short t[64][68];      // used by x4 path only
  const int tid = threadIdx.x;
  const int blk = blockIdx.x;

  if (blk < X4_BLKS) {
    // ---- prep_x4 body: x [b][c][2401] fp32 -> xb [b][row][256c] bf16 (masked)
    const int l = blk;
    const int span = l % 38, cg = (l / 38) & 3, b = l / 152;
    const int s0 = span * 64;
    {
      const int chl = tid >> 2, i4 = tid & 3;
      const float* src = x + ((size_t)(b * 256 + cg * 64 + chl)) * NPIX;
      const int rbase = s0 + i4 * 16;
#pragma unroll
      for (int it = 0; it < 4; ++it) {
        int r = rbase + it * 4;
        float vv[4] = {0.f, 0.f, 0.f, 0.f};
        if (r + 3 < NPIX) {
          float4 v = *(const float4*)(src + r);
          vv[0] = v.x; vv[1] = v.y; vv[2] = v.z; vv[3] = v.w;
        } else {
#pragma unroll
          for (int e = 0; e < 4; ++e) if (r + e < NPIX) vv[e] = src[r + e];
        }
        short4v u = {0, 0, 0, 0};
#pragma unroll
        for (int e = 0; e < 4; ++e) {
          int re = r + e;
          unsigned short uu = 0;
          if (re < NPIX) {
            int h = re / 49, ww = re - h * 49, s = h + ww;
            if (s >= 24 && s <= 72) uu = f2bf(vv[e]);
          }
          u[e] = (short)uu;
        }
        *(short4v*)&t[chl][i4 * 16 + it * 4] = u;
      }
    }
    __syncthreads();
    const int pp = tid >> 3;   // pixel pair 0..31
    const int co = tid & 7;    // channel octet 0..7
    unsigned d[8];
#pragma unroll
    for (int k = 0; k < 8; ++k) d[k] = *(const unsigned*)&t[co * 8 + k][pp * 2];
    uint4 lo, hi;
    {
      unsigned l0[4], h0[4];
#pragma unroll
      for (int m = 0; m < 4; ++m) {
        unsigned a = d[2 * m], bq = d[2 * m + 1];
        l0[m] = (a & 0xffffu) | (bq << 16);
        h0[m] = (a >> 16) | (bq & 0xffff0000u);
      }
      lo = make_uint4(l0[0], l0[1], l0[2], l0[3]);
      hi = make_uint4(h0[0], h0[1], h0[2], h0[3]);
    }
    const int r_lo = s0 + pp * 2, r_hi = r_lo + 1;
    if (r_lo < NPIX) {
      int prow = r_lo + r_lo / 49 + XBLEAD;
      *(uint4*)(xb + ((size_t)b * XBROWS + prow) * 256 + cg * 64 + co * 8) = lo;
    }
    if (r_hi < NPIX) {
      int prow = r_hi + r_hi / 49 + XBLEAD;
      *(uint4*)(xb + ((size_t)b * XBROWS + prow) * 256 + cg * 64 + co * 8) = hi;
    }
  } else if (blk < X4_BLKS + Z_BLKS) {
    // ---- zero_pads5 body: zero only the pad rows of xb
    int idx = (blk - X4_BLKS) * 256 + tid;
    if (idx >= 32 * NPADROW * 32) return;
    int c16 = idx & 31;
    int rr  = idx >> 5;
    int pr  = rr % NPADROW;
    int b   = rr / NPADROW;
    int row;
    if (pr < 56)        row = pr;
    else if (pr < 105)  row = 105 + 50 * (pr - 56);
    else                row = 2506 + (pr - 105);
    short8 z = {0,0,0,0,0,0,0,0};
    *(short8*)(xb + ((size_t)b * XBROWS + row) * 256 + c16 * 8) = z;
  } else {
    // ---- prep_w body
    prep_w_body(w, wp, (blk - X4_BLKS - Z_BLKS) * 256 + tid);
  }
}

// standalone w-pack for the fallback path (no xb workspace)
__global__ void prep_w_kernel(const float* __restrict__ w, unsigned short* __restrict__ wp) {
  prep_w_body(w, wp, blockIdx.x * 256 + threadIdx.x);
}

// ---------------- main v12 ----------------
__global__ __launch_bounds__(256, 4)
void hexconv_v12(const unsigned short* __restrict__ xb,
                 const unsigned short* __restrict__ wp,
                 const float* __restrict__ bias,
                 float* __restrict__ out) {
  __shared__ __attribute__((aligned(16))) unsigned char smem[2 * BUF12];  // 24576 B

  const int tid  = threadIdx.x;
  const int lane = tid & 63;
  const int wv   = tid >> 6;    // 0..3: 32-och subgroup within this och-half
  const int col  = lane & 15;
  const int quad = lane >> 4;

  // bx encodes (px-tile, och-half); oh varies fastest so both halves of a pt
  // are dispatched adjacently (xb window L2/L3 reuse). pt relabeled so each
  // XCD (bxp%8 under round-robin) owns 4 contiguous pt.
  const int bx  = blockIdx.x;         // 0..63
  const int oh  = bx & 1;             // och half: 0 -> och 0..127, 1 -> 128..255
  const int bxp = bx >> 1;            // 0..31
  const int pt  = (bxp & 7) * 4 + (bxp >> 3);
  const int b   = blockIdx.y;
  const int P0  = pt * PT12;
  const int phase = (pt + b + oh * 4) & 7;   // kc start offset: desync blocks

  // tap offsets in pitch-50 padded space
  const int OFF[7] = {0, 50, 1, -49, -50, -1, 49};

  // B-frag LDS base addresses (kc/j-invariant; j adds j*1024 = 16 rows)
  int ba[7];
#pragma unroll
  for (int n = 0; n < 7; ++n) {
    int r0 = col + 56 + OFF[n];              // 6..121 (< 192-row window)
    int r64 = r0 << 6;
    ba[n] = (r64 + quad * 16) ^ ((r64 >> 3) & 0x30);
  }

  // staging: within a seg, lane l covers row 16s+(l>>2), LDS part l&3 (HW-forced),
  // global part swizzled so compute-side XOR lands conflict-free
  const int gpart = (lane & 3) ^ ((lane >> 3) & 3);
  const char* gsrc0 = (const char*)(xb + ((size_t)b * XBROWS + (size_t)P0) * 256)
                      + (lane >> 2) * 512 + gpart * 16;

  // stage ONE kc into one buffer: 12 seg-units over 4 waves (3 each)
  auto stage1 = [&](int buf, int kc) {
    char* ldsb = (char*)smem + buf * BUF12;
    for (int u = wv; u < NSEG12; u += 4) {
      __builtin_amdgcn_global_load_lds(
          (const __attribute__((address_space(1))) unsigned int*)
              (gsrc0 + (size_t)u * 8192 + kc * 64),
          (__attribute__((address_space(3))) unsigned int*)(ldsb + u * 1024), 16, 0, 0);
    }
  };

  // A-frag base: this wave's 2 och tiles start at ot = oh*8 + wv*2
  const char* wbase = (const char*)wp + (size_t)(oh * 8 + wv * 2) * 1024 + lane * 16;

  floatx4 acc[2][5];
#pragma unroll
  for (int ii = 0; ii < 2; ++ii)
#pragma unroll
    for (int j = 0; j < 5; ++j) acc[ii][j] = (floatx4){0.f, 0.f, 0.f, 0.f};

  stage1(0, phase);
  __syncthreads();

  for (int i = 0; i < 8; ++i) {
    const int kc = (i + phase) & 7;
    if (i < 7) stage1((i + 1) & 1, (i + 1 + phase) & 7);
    const char* bufp = (const char*)smem + (i & 1) * BUF12;
#pragma unroll
    for (int n = 0; n < 7; ++n) {
      short8 af[2];
#pragma unroll
      for (int ii = 0; ii < 2; ++ii)
        af[ii] = *(const short8*)(wbase + ((size_t)((n * 8 + kc) * 16 + ii)) * 1024);
      const char* bp = bufp + ba[n];
      short8 bfv[5];
#pragma unroll
      for (int j = 0; j < 5; ++j)
        bfv[j] = *(const short8*)(bp + j * 1024);
      __builtin_amdgcn_s_setprio(1);
#pragma unroll
      for (int j = 0; j < 5; ++j)
#pragma unroll
        for (int ii = 0; ii < 2; ++ii)
          acc[ii][j] = __builtin_amdgcn_mfma_f32_16x16x32_bf16(af[ii], bfv[j], acc[ii][j], 0, 0, 0);
      __builtin_amdgcn_s_setprio(0);
    }
    if (i < 7) __syncthreads();
  }

  // epilogue: bias pre-add, masked store. o = oh*128 + wv*32 + ii*16 + quad*4 + rr,
  // padded pix = P0 + j*16 + col
  const int ob = oh * 128 + wv * 32;
#pragma unroll
  for (int ii = 0; ii < 2; ++ii) {
    floatx4 bv = *(const floatx4*)(bias + ob + ii * 16 + quad * 4);
#pragma unroll
    for (int j = 0; j < 5; ++j)
#pragma unroll
      for (int rr = 0; rr < 4; ++rr) acc[ii][j][rr] += bv[rr];
  }

#pragma unroll
  for (int j = 0; j < 5; ++j) {
    int p = P0 + j * 16 + col;
    int h = p / W50;
    int w = p - h * W50;
    if (w >= 49 || p >= PREAL) continue;
    bool m = (h + w >= 24) && (h + w <= 72);
    int ridx = h * 49 + w;
#pragma unroll
    for (int ii = 0; ii < 2; ++ii) {
      float* dst = out + ((b * 256 + ob + ii * 16 + quad * 4) * NPIX + ridx);
#pragma unroll
      for (int rr = 0; rr < 4; ++rr) {
        float v = m ? acc[ii][j][rr] : 0.f;
        dst[rr * NPIX] = v;
      }
    }
  }
}

// ---------------- fallback v1 (ws too small) ----------------
#define PITCH  40
#define V1WIN  168
#define V1ZROW 168
__global__ __launch_bounds__(256)
void hexconv_v1(const float* __restrict__ x,
                const unsigned short* __restrict__ wp,
                const float* __restrict__ bias,
                float* __restrict__ out) {
  __shared__ unsigned short sm[(V1ZROW + 2) * PITCH];
  const int tid = threadIdx.x, lane = tid & 63, wv = tid >> 6;
  const int col = lane & 15, quad = lane >> 4;
  const int pt = blockIdx.x, b = blockIdx.y;
  const int P0 = pt * 64, win_start = P0 - 52;
  if (tid < PITCH * 2) sm[V1ZROW * PITCH + tid] = 0;
  const int OFF[7] = {0, 49, 1, -48, -49, -1, 48};
  const int DXP = (1 << 2) | (1 << 3), DXN = (1 << 5) | (1 << 6);
  int baddr[4][7];
#pragma unroll
  for (int j = 0; j < 4; ++j) {
    int pix = P0 + j * 16 + col;
    int wj = pix % 49;
    int rowbase = pix - win_start;
#pragma unroll
    for (int n = 0; n < 7; ++n) {
      bool bad = (((DXP >> n) & 1) && wj == 48) || (((DXN >> n) & 1) && wj == 0);
      int row = bad ? V1ZROW : (rowbase + OFF[n]);
      baddr[j][n] = row * (PITCH * 2) + quad * 16;
    }
  }
  int sp[3], sgp[3]; bool sok[3];
#pragma unroll
  for (int pi = 0; pi < 3; ++pi) {
    int p = lane + pi * 64, gp = win_start + p;
    sp[pi] = p; sgp[pi] = gp;
    bool hm = false;
    if (gp >= 0 && gp < NPIX) { int h = gp / 49, w = gp - h * 49, s = h + w; hm = (s >= 24 && s <= 72); }
    sok[pi] = (p < V1WIN) && hm;
  }
  floatx4 acc[4][4];
#pragma unroll
  for (int i = 0; i < 4; ++i)
#pragma unroll
    for (int j = 0; j < 4; ++j) acc[i][j] = (floatx4){0.f, 0.f, 0.f, 0.f};
  const short8* wpv = (const short8*)wp;
  const int wslot = wv * 4;
  for (int kc = 0; kc < 8; ++kc) {
    __syncthreads();
#pragma unroll
    for (int ci = 0; ci < 8; ++ci) {
      int c = ci * 4 + wv;
      const float* src = x + ((size_t)(b * 256 + kc * 32 + c)) * NPIX;
#pragma unroll
      for (int pi = 0; pi < 3; ++pi) {
        if (sp[pi] < V1WIN) {
          float v = sok[pi] ? src[sgp[pi]] : 0.f;
          sm[sp[pi] * PITCH + c] = f2bf(v);
        }
      }
    }
    __syncthreads();
#pragma unroll
    for (int n = 0; n < 7; ++n) {
      short8 af[4];
#pragma unroll
      for (int i = 0; i < 4; ++i)
        af[i] = wpv[((size_t)((n * 8 + kc) * 16 + wslot + i)) * 64 + lane];
      short8 bf[4];
#pragma unroll
      for (int j = 0; j < 4; ++j)
        bf[j] = *(const short8*)((const char*)sm + baddr[j][n]);
#pragma unroll
      for (int i = 0; i < 4; ++i)
#pragma unroll
        for (int j = 0; j < 4; ++j)
          acc[i][j] = __builtin_amdgcn_mfma_f32_16x16x32_bf16(af[i], bf[j], acc[i][j], 0, 0, 0);
    }
  }
  const int ob = wv * 64;
  floatx4 bv[4];
#pragma unroll
  for (int i = 0; i < 4; ++i)
    bv[i] = *(const floatx4*)(bias + ob + i * 16 + quad * 4);
#pragma unroll
  for (int j = 0; j < 4; ++j) {
    int pix = P0 + j * 16 + col;
    if (pix >= NPIX) continue;
    int h = pix / 49, w = pix - h * 49;
    bool m = (h + w >= 24 && h + w <= 72);
#pragma unroll
    for (int i = 0; i < 4; ++i) {
      int o = ob + i * 16 + quad * 4;
      float* dst = out + ((size_t)(b * 256 + o)) * NPIX + pix;
#pragma unroll
      for (int r = 0; r < 4; ++r) {
        float v = m ? (acc[i][j][r] + bv[i][r]) : 0.f;
        dst[(size_t)r * NPIX] = v;
      }
    }
  }
}

extern "C" void kernel_launch(void* const* d_in, const int* in_sizes, int n_in,
                              void* d_out, int out_size, void* d_ws, size_t ws_size,
                              hipStream_t stream) {
  const float* x    = (const float*)d_in[0];   // [32,256,49,49]
  const float* w    = (const float*)d_in[1];   // [256,256,7]
  const float* bias = (const float*)d_in[2];   // [256]
  float* out = (float*)d_out;

  if (ws_size >= WS_NEED3) {
    unsigned short* xb = (unsigned short*)d_ws;
    unsigned short* wp = (unsigned short*)((char*)d_ws + XB3_BYTES);
    prep_all<<<PREP_BLKS, 256, 0, stream>>>(x, w, xb, wp);
    hexconv_v12<<<dim3(64, 32), 256, 0, stream>>>(xb, wp, bias, out);
  } else {
    unsigned short* wp = (unsigned short*)d_ws;
    prep_w_kernel<<<224, 256, 0, stream>>>(w, wp);
    hexconv_v1<<<dim3(38, 32), 256, 0, stream>>>(x, wp, bias, out);
  }
}

// Round 7
// 231.339 us; speedup vs baseline: 1.0241x; 1.0241x over previous
//
#include <hip/hip_runtime.h>

// HexConv2d implicit GEMM, bf16 MFMA 16x16x32.
// v13: remove VMEM from the MFMA consume path. Evidence chain: occupancy
// 17->40% (v6->v12) left MfmaUtil pinned at 35-40% -> occupancy was never the
// limiter; the 2-phase stage/wait/barrier structure is (we sit at 905 TF, the
// known ceiling of that structure). Changes, all in the verified skeleton:
//  1) af REGISTER RING: tap n+1's 4 weight frags load into regs during tap n's
//     20 MFMAs (ring slot (n+iter)&1, compile-time via pair-unroll). Inner loop
//     consumes registers + LDS only -> no vmcnt wait per step (in-order vmcnt
//     retirement made af consumes wait behind staging before).
//  2) och-64/wave, full 256-och block (v11 economics): bf ds_read feeds 4
//     MFMAs -> chip LDS time halves vs v12 (43->22us floor); xb staged once
//     -> FETCH back to ~42MB. acc[4][5]=80 + ring 32 -> ~190 regs, 2 waves/
//     SIMD from 2 DIFFERENT blocks (grid 1024 = 2 clean rounds of 512).
//  3) 3-slot LDS ring, staging 2 iters ahead: buffer consumed at iter i was
//     issued at iter i-2 (~2 compute phases of cover) -> the barrier's
//     vmcnt(0) drain costs ~0 without hand-rolled barriers.
// Accumulation order (kc outer, taps inner) identical to v12 -> same absmax.

typedef __attribute__((ext_vector_type(8))) short short8;
typedef __attribute__((ext_vector_type(4))) short short4v;
typedef __attribute__((ext_vector_type(4))) float floatx4;

#define NPIX   2401
#define W50    50
#define PREAL  2450      // 49 rows * 50
#define XBLEAD 56
#define XBROWS 2672      // padded rows per batch: [-56, 2616)
#define PT13   80        // pixels per block
#define NSEG13 12        // 192 window rows: [P0-56, P0+136); max tap row 185
#define BUF13  (NSEG13*1024)      // 12288 B per kc slot
#define XB3_BYTES ((size_t)32*XBROWS*256*2)   // 43,778,048
#define WP_BYTES  917504ULL
#define WS_NEED3  (XB3_BYTES + WP_BYTES)
#define NPADROW 271      // 56 apron + 49 col-49 + 166 tail rows per batch

// merged-prep block ranges
#define X4_BLKS 4864     // 38*4*32
#define Z_BLKS  1084     // 32*271*32 / 256 = 1084 exactly
#define W_BLKS  224
#define PREP_BLKS (X4_BLKS + Z_BLKS + W_BLKS)   // 6172

__device__ __forceinline__ unsigned short f2bf(float f) {
  unsigned u = __builtin_bit_cast(unsigned, f);
  u += 0x7fffu + ((u >> 16) & 1u);          // RNE
  return (unsigned short)(u >> 16);
}

__device__ __forceinline__ void prep_w_body(const float* __restrict__ w,
                                            unsigned short* __restrict__ wp, int tt) {
  int l  = tt & 63;
  int ot = (tt >> 6) & 15;
  int kc = (tt >> 10) & 7;
  int n  = tt >> 13;
  int o  = ot * 16 + (l & 15);
  int cb = kc * 32 + ((l >> 4) * 8);
  const float* src = w + (size_t)(o * 256 + cb) * 7 + n;
  short8 pk;
#pragma unroll
  for (int j = 0; j < 8; ++j) pk[j] = (short)f2bf(src[j * 7]);
  ((short8*)wp)[tt] = pk;
}

// ---------------- merged prep: x-transpose | pad-zero | w-pack ----------------
__global__ __launch_bounds__(256)
void prep_all(const float* __restrict__ x, const float* __restrict__ w,
              unsigned short* __restrict__ xb, unsigned short* __restrict__ wp) {
  __shared__ unsigned short t[64][68];      // used by x4 path only
  const int tid = threadIdx.x;
  const int blk = blockIdx.x;

  if (blk < X4_BLKS) {
    // ---- prep_x4 body: x [b][c][2401] fp32 -> xb [b][row][256c] bf16 (masked)
    const int l = blk;
    const int span = l % 38, cg = (l / 38) & 3, b = l / 152;
    const int s0 = span * 64;
    {
      const int chl = tid >> 2, i4 = tid & 3;
      const float* src = x + ((size_t)(b * 256 + cg * 64 + chl)) * NPIX;
      const int rbase = s0 + i4 * 16;
#pragma unroll
      for (int it = 0; it < 4; ++it) {
        int r = rbase + it * 4;
        float vv[4] = {0.f, 0.f, 0.f, 0.f};
        if (r + 3 < NPIX) {
          float4 v = *(const float4*)(src + r);
          vv[0] = v.x; vv[1] = v.y; vv[2] = v.z; vv[3] = v.w;
        } else {
#pragma unroll
          for (int e = 0; e < 4; ++e) if (r + e < NPIX) vv[e] = src[r + e];
        }
        short4v u = {0, 0, 0, 0};
#pragma unroll
        for (int e = 0; e < 4; ++e) {
          int re = r + e;
          unsigned short uu = 0;
          if (re < NPIX) {
            int h = re / 49, ww = re - h * 49, s = h + ww;
            if (s >= 24 && s <= 72) uu = f2bf(vv[e]);
          }
          u[e] = (short)uu;
        }
        *(short4v*)&t[chl][i4 * 16 + it * 4] = u;
      }
    }
    __syncthreads();
    const int pp = tid >> 3;   // pixel pair 0..31
    const int co = tid & 7;    // channel octet 0..7
    unsigned d[8];
#pragma unroll
    for (int k = 0; k < 8; ++k) d[k] = *(const unsigned*)&t[co * 8 + k][pp * 2];
    uint4 lo, hi;
    {
      unsigned l0[4], h0[4];
#pragma unroll
      for (int m = 0; m < 4; ++m) {
        unsigned a = d[2 * m], bq = d[2 * m + 1];
        l0[m] = (a & 0xffffu) | (bq << 16);
        h0[m] = (a >> 16) | (bq & 0xffff0000u);
      }
      lo = make_uint4(l0[0], l0[1], l0[2], l0[3]);
      hi = make_uint4(h0[0], h0[1], h0[2], h0[3]);
    }
    const int r_lo = s0 + pp * 2, r_hi = r_lo + 1;
    if (r_lo < NPIX) {
      int prow = r_lo + r_lo / 49 + XBLEAD;
      *(uint4*)(xb + ((size_t)b * XBROWS + prow) * 256 + cg * 64 + co * 8) = lo;
    }
    if (r_hi < NPIX) {
      int prow = r_hi + r_hi / 49 + XBLEAD;
      *(uint4*)(xb + ((size_t)b * XBROWS + prow) * 256 + cg * 64 + co * 8) = hi;
    }
  } else if (blk < X4_BLKS + Z_BLKS) {
    // ---- zero_pads5 body: zero only the pad rows of xb
    int idx = (blk - X4_BLKS) * 256 + tid;
    if (idx >= 32 * NPADROW * 32) return;
    int c16 = idx & 31;
    int rr  = idx >> 5;
    int pr  = rr % NPADROW;
    int b   = rr / NPADROW;
    int row;
    if (pr < 56)        row = pr;
    else if (pr < 105)  row = 105 + 50 * (pr - 56);
    else                row = 2506 + (pr - 105);
    short8 z = {0,0,0,0,0,0,0,0};
    *(short8*)(xb + ((size_t)b * XBROWS + row) * 256 + c16 * 8) = z;
  } else {
    // ---- prep_w body
    prep_w_body(w, wp, (blk - X4_BLKS - Z_BLKS) * 256 + tid);
  }
}

// standalone w-pack for the fallback path (no xb workspace)
__global__ void prep_w_kernel(const float* __restrict__ w, unsigned short* __restrict__ wp) {
  prep_w_body(w, wp, blockIdx.x * 256 + threadIdx.x);
}

// one kc-iteration: consume af ring parity JPAR, prefetch next tap's frags.
// DO_STAGE: issue stage for iter i+2. DO_PRE_LAST: at tap 6, prefetch tap0 of
// the NEXT kc (skipped only on the final iteration).
#define HEX_ITER(IVAL, JPAR, DO_STAGE, DO_PRE_LAST)                           \
  {                                                                           \
    const int i_ = (IVAL);                                                    \
    if (DO_STAGE) stage1((i_ + 2) % 3, (i_ + 2 + phase) & 7);                 \
    const int kcc_ = (i_ + phase) & 7;                                        \
    const int kcn_ = (i_ + 1 + phase) & 7;                                    \
    const char* bufp_ = (const char*)smem + (i_ % 3) * BUF13;                 \
    _Pragma("unroll")                                                         \
    for (int n = 0; n < 7; ++n) {                                             \
      const int cs = (n + (JPAR)) & 1;                                        \
      const int ns = cs ^ 1;                                                  \
      if (n < 6) {                                                            \
        _Pragma("unroll")                                                     \
        for (int ii = 0; ii < 4; ++ii)                                        \
          afr[ns][ii] = *(const short8*)(wbase +                              \
              (size_t)(((n + 1) * 8 + kcc_) * 16 + ii) * 1024);               \
      } else if (DO_PRE_LAST) {                                               \
        _Pragma("unroll")                                                     \
        for (int ii = 0; ii < 4; ++ii)                                        \
          afr[ns][ii] = *(const short8*)(wbase +                              \
              (size_t)((kcn_ * 16) + ii) * 1024);                             \
      }                                                                       \
      const char* bp_ = bufp_ + ba[n];                                        \
      short8 bfv[5];                                                          \
      _Pragma("unroll")                                                       \
      for (int j = 0; j < 5; ++j) bfv[j] = *(const short8*)(bp_ + j * 1024);  \
      __builtin_amdgcn_s_setprio(1);                                          \
      _Pragma("unroll")                                                       \
      for (int j = 0; j < 5; ++j)                                             \
        _Pragma("unroll")                                                     \
        for (int ii = 0; ii < 4; ++ii)                                        \
          acc[ii][j] = __builtin_amdgcn_mfma_f32_16x16x32_bf16(               \
              afr[cs][ii], bfv[j], acc[ii][j], 0, 0, 0);                      \
      __builtin_amdgcn_s_setprio(0);                                          \
    }                                                                         \
  }

// ---------------- main v13 ----------------
__global__ __launch_bounds__(256, 2)
void hexconv_v13(const unsigned short* __restrict__ xb,
                 const unsigned short* __restrict__ wp,
                 const float* __restrict__ bias,
                 float* __restrict__ out) {
  __shared__ __attribute__((aligned(16))) unsigned char smem[3 * BUF13];  // 36864 B

  const int tid  = threadIdx.x;
  const int lane = tid & 63;
  const int wv   = tid >> 6;    // 0..3: wave owns och [wv*64, wv*64+64)
  const int col  = lane & 15;
  const int quad = lane >> 4;

  // pt relabel: XCD x (= bx%8 under round-robin dispatch) owns pt in [4x,4x+4)
  const int bx = blockIdx.x;          // 0..31
  const int pt = (bx & 7) * 4 + (bx >> 3);
  const int b  = blockIdx.y;
  const int P0 = pt * PT13;
  const int phase = (pt + b) & 7;     // kc start offset: desync blocks

  // tap offsets in pitch-50 padded space
  const int OFF[7] = {0, 50, 1, -49, -50, -1, 49};

  // B-frag LDS base addresses within a kc slot (j adds j*1024 = 16 rows)
  int ba[7];
#pragma unroll
  for (int n = 0; n < 7; ++n) {
    int r0 = col + 56 + OFF[n];              // 6..121 (< 192-row window)
    int r64 = r0 << 6;
    ba[n] = (r64 + quad * 16) ^ ((r64 >> 3) & 0x30);
  }

  // staging: within a seg, lane l covers row 16s+(l>>2), LDS part l&3 (HW-forced),
  // global part swizzled so compute-side XOR lands conflict-free
  const int gpart = (lane & 3) ^ ((lane >> 3) & 3);
  const char* gsrc0 = (const char*)(xb + ((size_t)b * XBROWS + (size_t)P0) * 256)
                      + (lane >> 2) * 512 + gpart * 16;

  // stage ONE kc into slot: 12 seg-units over 4 waves (3 each)
  auto stage1 = [&](int slot, int kc) {
    char* ldsb = (char*)smem + slot * BUF13;
    for (int u = wv; u < NSEG13; u += 4) {
      __builtin_amdgcn_global_load_lds(
          (const __attribute__((address_space(1))) unsigned int*)
              (gsrc0 + (size_t)u * 8192 + kc * 64),
          (__attribute__((address_space(3))) unsigned int*)(ldsb + u * 1024), 16, 0, 0);
    }
  };

  // A-frag base: this wave's 4 och tiles start at ot = wv*4
  const char* wbase = (const char*)wp + (size_t)(wv * 4) * 1024 + lane * 16;

  short8 afr[2][4];          // af ring: 2 tap-sets x 4 och-tiles (32 VGPR)
  floatx4 acc[4][5];
#pragma unroll
  for (int ii = 0; ii < 4; ++ii)
#pragma unroll
    for (int j = 0; j < 5; ++j) acc[ii][j] = (floatx4){0.f, 0.f, 0.f, 0.f};

  // prologue: stage kc0->slot0, kc1->slot1; preload tap0 frags of kc0
  stage1(0, phase);
  stage1(1, (1 + phase) & 7);
#pragma unroll
  for (int ii = 0; ii < 4; ++ii)
    afr[0][ii] = *(const short8*)(wbase + (size_t)((phase * 16) + ii) * 1024);
  __syncthreads();

#pragma unroll 1
  for (int p = 0; p < 3; ++p) {
    HEX_ITER(2 * p,     0, true, true);
    __syncthreads();
    HEX_ITER(2 * p + 1, 1, true, true);
    __syncthreads();
  }
  HEX_ITER(6, 0, false, true);
  __syncthreads();
  HEX_ITER(7, 1, false, false);

  // epilogue: bias pre-add, masked store. o = wv*64+ii*16+quad*4+rr,
  // padded pix = P0 + j*16 + col
  const int ob = wv * 64;
#pragma unroll
  for (int ii = 0; ii < 4; ++ii) {
    floatx4 bv = *(const floatx4*)(bias + ob + ii * 16 + quad * 4);
#pragma unroll
    for (int j = 0; j < 5; ++j)
#pragma unroll
      for (int rr = 0; rr < 4; ++rr) acc[ii][j][rr] += bv[rr];
  }

#pragma unroll
  for (int j = 0; j < 5; ++j) {
    int p = P0 + j * 16 + col;
    int h = p / W50;
    int w = p - h * W50;
    if (w >= 49 || p >= PREAL) continue;
    bool m = (h + w >= 24) && (h + w <= 72);
    int ridx = h * 49 + w;
#pragma unroll
    for (int ii = 0; ii < 4; ++ii) {
      float* dst = out + ((b * 256 + ob + ii * 16 + quad * 4) * NPIX + ridx);
#pragma unroll
      for (int rr = 0; rr < 4; ++rr) {
        float v = m ? acc[ii][j][rr] : 0.f;
        dst[rr * NPIX] = v;
      }
    }
  }
}

// ---------------- fallback v1 (ws too small) ----------------
#define PITCH  40
#define V1WIN  168
#define V1ZROW 168
__global__ __launch_bounds__(256)
void hexconv_v1(const float* __restrict__ x,
                const unsigned short* __restrict__ wp,
                const float* __restrict__ bias,
                float* __restrict__ out) {
  __shared__ unsigned short sm[(V1ZROW + 2) * PITCH];
  const int tid = threadIdx.x, lane = tid & 63, wv = tid >> 6;
  const int col = lane & 15, quad = lane >> 4;
  const int pt = blockIdx.x, b = blockIdx.y;
  const int P0 = pt * 64, win_start = P0 - 52;
  if (tid < PITCH * 2) sm[V1ZROW * PITCH + tid] = 0;
  const int OFF[7] = {0, 49, 1, -48, -49, -1, 48};
  const int DXP = (1 << 2) | (1 << 3), DXN = (1 << 5) | (1 << 6);
  int baddr[4][7];
#pragma unroll
  for (int j = 0; j < 4; ++j) {
    int pix = P0 + j * 16 + col;
    int wj = pix % 49;
    int rowbase = pix - win_start;
#pragma unroll
    for (int n = 0; n < 7; ++n) {
      bool bad = (((DXP >> n) & 1) && wj == 48) || (((DXN >> n) & 1) && wj == 0);
      int row = bad ? V1ZROW : (rowbase + OFF[n]);
      baddr[j][n] = row * (PITCH * 2) + quad * 16;
    }
  }
  int sp[3], sgp[3]; bool sok[3];
#pragma unroll
  for (int pi = 0; pi < 3; ++pi) {
    int p = lane + pi * 64, gp = win_start + p;
    sp[pi] = p; sgp[pi] = gp;
    bool hm = false;
    if (gp >= 0 && gp < NPIX) { int h = gp / 49, w = gp - h * 49, s = h + w; hm = (s >= 24 && s <= 72); }
    sok[pi] = (p < V1WIN) && hm;
  }
  floatx4 acc[4][4];
#pragma unroll
  for (int i = 0; i < 4; ++i)
#pragma unroll
    for (int j = 0; j < 4; ++j) acc[i][j] = (floatx4){0.f, 0.f, 0.f, 0.f};
  const short8* wpv = (const short8*)wp;
  const int wslot = wv * 4;
  for (int kc = 0; kc < 8; ++kc) {
    __syncthreads();
#pragma unroll
    for (int ci = 0; ci < 8; ++ci) {
      int c = ci * 4 + wv;
      const float* src = x + ((size_t)(b * 256 + kc * 32 + c)) * NPIX;
#pragma unroll
      for (int pi = 0; pi < 3; ++pi) {
        if (sp[pi] < V1WIN) {
          float v = sok[pi] ? src[sgp[pi]] : 0.f;
          sm[sp[pi] * PITCH + c] = f2bf(v);
        }
      }
    }
    __syncthreads();
#pragma unroll
    for (int n = 0; n < 7; ++n) {
      short8 af[4];
#pragma unroll
      for (int i = 0; i < 4; ++i)
        af[i] = wpv[((size_t)((n * 8 + kc) * 16 + wslot + i)) * 64 + lane];
      short8 bf[4];
#pragma unroll
      for (int j = 0; j < 4; ++j)
        bf[j] = *(const short8*)((const char*)sm + baddr[j][n]);
#pragma unroll
      for (int i = 0; i < 4; ++i)
#pragma unroll
        for (int j = 0; j < 4; ++j)
          acc[i][j] = __builtin_amdgcn_mfma_f32_16x16x32_bf16(af[i], bf[j], acc[i][j], 0, 0, 0);
    }
  }
  const int ob = wv * 64;
  floatx4 bv[4];
#pragma unroll
  for (int i = 0; i < 4; ++i)
    bv[i] = *(const floatx4*)(bias + ob + i * 16 + quad * 4);
#pragma unroll
  for (int j = 0; j < 4; ++j) {
    int pix = P0 + j * 16 + col;
    if (pix >= NPIX) continue;
    int h = pix / 49, w = pix - h * 49;
    bool m = (h + w >= 24 && h + w <= 72);
#pragma unroll
    for (int i = 0; i < 4; ++i) {
      int o = ob + i * 16 + quad * 4;
      float* dst = out + ((size_t)(b * 256 + o)) * NPIX + pix;
#pragma unroll
      for (int r = 0; r < 4; ++r) {
        float v = m ? (acc[i][j][r] + bv[i][r]) : 0.f;
        dst[(size_t)r * NPIX] = v;
      }
    }
  }
}

extern "C" void kernel_launch(void* const* d_in, const int* in_sizes, int n_in,
                              void* d_out, int out_size, void* d_ws, size_t ws_size,
                              hipStream_t stream) {
  const float* x    = (const float*)d_in[0];   // [32,256,49,49]
  const float* w    = (const float*)d_in[1];   // [256,256,7]
  const float* bias = (const float*)d_in[2];   // [256]
  float* out = (float*)d_out;

  if (ws_size >= WS_NEED3) {
    unsigned short* xb = (unsigned short*)d_ws;
    unsigned short* wp = (unsigned short*)((char*)d_ws + XB3_BYTES);
    prep_all<<<PREP_BLKS, 256, 0, stream>>>(x, w, xb, wp);
    hexconv_v13<<<dim3(32, 32), 256, 0, stream>>>(xb, wp, bias, out);
  } else {
    unsigned short* wp = (unsigned short*)d_ws;
    prep_w_kernel<<<224, 256, 0, stream>>>(w, wp);
    hexconv_v1<<<dim3(38, 32), 256, 0, stream>>>(x, wp, bias, out);
  }
}